// Round 5
// baseline (538.304 us; speedup 1.0000x reference)
//
#include <hip/hip_runtime.h>

#define GRAPHS 128

typedef _Float16 f16x8 __attribute__((ext_vector_type(8)));
typedef _Float16 f16x4 __attribute__((ext_vector_type(4)));
typedef _Float16 f16x2 __attribute__((ext_vector_type(2)));
typedef float f32x4 __attribute__((ext_vector_type(4)));

// ---------------- CSR build (by dst), reused for both convs ----------------
__global__ void k_count(const int* __restrict__ dst, int* __restrict__ deg, int e) {
  int i = blockIdx.x * 256 + threadIdx.x;
  if (i < e) atomicAdd(&deg[dst[i]], 1);
}

__global__ void k_scan1(const int* __restrict__ deg, int* __restrict__ bs, int n) {
  __shared__ int s[256];
  int t = threadIdx.x;
  int base = blockIdx.x * 1024 + t * 4;
  int sum = 0;
#pragma unroll
  for (int j = 0; j < 4; ++j) { int i = base + j; if (i < n) sum += deg[i]; }
  s[t] = sum; __syncthreads();
  for (int off = 128; off > 0; off >>= 1) {
    if (t < off) s[t] += s[t + off];
    __syncthreads();
  }
  if (t == 0) bs[blockIdx.x] = s[0];
}

__global__ void k_scan2(int* bs, int nb) {  // 1 block, nb <= 256
  __shared__ int s[256];
  int t = threadIdx.x;
  int v = (t < nb) ? bs[t] : 0;
  s[t] = v; __syncthreads();
  for (int off = 1; off < 256; off <<= 1) {
    int x = (t >= off) ? s[t - off] : 0;
    __syncthreads();
    s[t] += x;
    __syncthreads();
  }
  if (t < nb) bs[t] = s[t] - v;  // exclusive block offsets
}

__global__ void k_scan3(const int* __restrict__ deg, const int* __restrict__ bs,
                        int* __restrict__ ptr, int* __restrict__ cur, int n, int e) {
  __shared__ int s[256];
  int t = threadIdx.x, b = blockIdx.x;
  int base = b * 1024 + t * 4;
  int v[4]; int tot = 0;
#pragma unroll
  for (int j = 0; j < 4; ++j) { int i = base + j; v[j] = (i < n) ? deg[i] : 0; tot += v[j]; }
  s[t] = tot; __syncthreads();
  for (int off = 1; off < 256; off <<= 1) {
    int x = (t >= off) ? s[t - off] : 0;
    __syncthreads();
    s[t] += x;
    __syncthreads();
  }
  int off = bs[b] + s[t] - tot;
#pragma unroll
  for (int j = 0; j < 4; ++j) {
    int i = base + j;
    if (i < n) { ptr[i] = off; cur[i] = off; off += v[j]; }
  }
  if (b == 0 && t == 0) ptr[n] = e;
}

// csr scatter via atomicExch: executes at L2 and allocates the line, avoiding
// the 64B/edge write-through HBM traffic a plain 4B scattered store causes
// (round-4 rocprof: WRITE_SIZE = e*64B on k_fill).
__global__ void k_fill(const int* __restrict__ src, const int* __restrict__ dst,
                       int* __restrict__ cur, int* __restrict__ csr, int e) {
  int i = blockIdx.x * 256 + threadIdx.x;
  if (i < e) { int pos = atomicAdd(&cur[dst[i]], 1); atomicExch(&csr[pos], src[i]); }
}

// ---------------- fp32 -> f16 conversion (x only) ----------------
__global__ void k_cvt(const float* __restrict__ in, _Float16* __restrict__ out, int total4) {
  int i = blockIdx.x * 256 + threadIdx.x;
  if (i >= total4) return;
  float4 v = ((const float4*)in)[i];
  f16x4 h = { (_Float16)v.x, (_Float16)v.y, (_Float16)v.z, (_Float16)v.w };
  ((f16x4*)out)[i] = h;
}

// ------------- aggregation (f16 in/out, fp32 accum): out[i] = in[i] + sum_N in[j] -------------
// one wave per node, 2 channels per lane; 8x-unrolled independent loads for MLP
__global__ void k_agg_h(const _Float16* __restrict__ in, _Float16* __restrict__ out,
                        const int* __restrict__ ptr, const int* __restrict__ csr, int n) {
  int gid = blockIdx.x * 256 + threadIdx.x;
  int node = gid >> 6, lane = gid & 63;
  if (node >= n) return;
  const f16x2* inp = (const f16x2*)in;
  f16x2 v = inp[(size_t)node * 64 + lane];
  float ax[8], ay[8];
  ax[0] = (float)v[0]; ay[0] = (float)v[1];
#pragma unroll
  for (int i = 1; i < 8; ++i) { ax[i] = 0.f; ay[i] = 0.f; }
  int s = ptr[node], e2 = ptr[node + 1];
  int idx = s;
  for (; idx + 8 <= e2; idx += 8) {
    f16x2 w[8];
#pragma unroll
    for (int u = 0; u < 8; ++u) w[u] = inp[(size_t)csr[idx + u] * 64 + lane];
#pragma unroll
    for (int u = 0; u < 8; ++u) { ax[u] += (float)w[u][0]; ay[u] += (float)w[u][1]; }
  }
  if (idx + 4 <= e2) {
    f16x2 w[4];
#pragma unroll
    for (int u = 0; u < 4; ++u) w[u] = inp[(size_t)csr[idx + u] * 64 + lane];
#pragma unroll
    for (int u = 0; u < 4; ++u) { ax[u] += (float)w[u][0]; ay[u] += (float)w[u][1]; }
    idx += 4;
  }
  for (; idx < e2; ++idx) {
    f16x2 w0 = inp[(size_t)csr[idx] * 64 + lane];
    ax[0] += (float)w0[0]; ay[0] += (float)w0[1];
  }
  float rx = ((ax[0] + ax[1]) + (ax[2] + ax[3])) + ((ax[4] + ax[5]) + (ax[6] + ax[7]));
  float ry = ((ay[0] + ay[1]) + (ay[2] + ay[3])) + ((ay[4] + ay[5]) + (ay[6] + ay[7]));
  f16x2 r = { (_Float16)rx, (_Float16)ry };
  ((f16x2*)out)[(size_t)node * 64 + lane] = r;
}

// -------- weight prep: W[k][c] fp32 -> Wt[c][k] f16 (grid = C, 128 threads) --------
__global__ void k_wprep(const float* __restrict__ W, _Float16* __restrict__ Wt, int C) {
  int c = blockIdx.x, k = threadIdx.x;
  Wt[c * 128 + k] = (_Float16)W[k * C + c];
}

// ------------- MFMA f16 GEMM: out = relu(in @ W + b), 128 -> 128, f16 in/out -------------
__launch_bounds__(256)
__global__ void k_gemm128_f16(const _Float16* __restrict__ in, const _Float16* __restrict__ Wt,
                              const float* __restrict__ bias, _Float16* __restrict__ out, int n) {
  __shared__ _Float16 xs[128 * 136];
  __shared__ _Float16 wt[128 * 136];
  int t = threadIdx.x;
  int r0 = blockIdx.x * 128;
#pragma unroll
  for (int i = 0; i < 8; ++i) {
    int id = t + i * 256;           // 0..2047 = 128 rows x 16 chunks
    int row = id >> 4, k8 = id & 15;
    f16x8 v = {0, 0, 0, 0, 0, 0, 0, 0};
    if (r0 + row < n) v = ((const f16x8*)in)[(size_t)(r0 + row) * 16 + k8];
    *(f16x8*)&xs[row * 136 + k8 * 8] = v;
  }
#pragma unroll
  for (int i = 0; i < 8; ++i) {
    int id = t + i * 256;           // 0..2047 = 128 cols x 16 chunks
    int c = id >> 4, k8 = id & 15;
    *(f16x8*)&wt[c * 136 + k8 * 8] = ((const f16x8*)Wt)[c * 16 + k8];
  }
  __syncthreads();
  int lane = t & 63, w = t >> 6;
  int l16 = lane & 15, lk = (lane >> 4) * 8;
  int rw = w * 32;
  f32x4 acc[2][8];
#pragma unroll
  for (int fr = 0; fr < 2; ++fr)
#pragma unroll
    for (int fc = 0; fc < 8; ++fc) acc[fr][fc] = (f32x4){0.f, 0.f, 0.f, 0.f};
#pragma unroll
  for (int kk = 0; kk < 4; ++kk) {
    int klo = kk * 32 + lk;
    f16x8 a0 = *(const f16x8*)&xs[(rw + l16) * 136 + klo];
    f16x8 a1 = *(const f16x8*)&xs[(rw + 16 + l16) * 136 + klo];
#pragma unroll
    for (int fc = 0; fc < 8; ++fc) {
      f16x8 b = *(const f16x8*)&wt[(fc * 16 + l16) * 136 + klo];
      acc[0][fc] = __builtin_amdgcn_mfma_f32_16x16x32_f16(a0, b, acc[0][fc], 0, 0, 0);
      acc[1][fc] = __builtin_amdgcn_mfma_f32_16x16x32_f16(a1, b, acc[1][fc], 0, 0, 0);
    }
  }
  int rbase = r0 + rw + (lane >> 4) * 4;
#pragma unroll
  for (int fr = 0; fr < 2; ++fr)
#pragma unroll
    for (int fc = 0; fc < 8; ++fc) {
      int col = fc * 16 + l16;
      float bv = bias[col];
#pragma unroll
      for (int j = 0; j < 4; ++j) {
        int row = rbase + fr * 16 + j;
        if (row < n) out[(size_t)row * 128 + col] = (_Float16)fmaxf(acc[fr][fc][j] + bv, 0.f);
      }
    }
}

// ------- final GEMM 128 -> 256 (two 128-col chunks) fused with mean-pool sums -------
__launch_bounds__(256)
__global__ void k_gemm_pool_f16(const _Float16* __restrict__ in, const _Float16* __restrict__ Wt,
                                const float* __restrict__ bias, const int* __restrict__ batch,
                                float* __restrict__ pool, int n) {
  __shared__ _Float16 xs[128 * 136];
  __shared__ _Float16 wt[128 * 136];
  __shared__ float pool_l[8 * 256];
  int t = threadIdx.x;
  int r0 = blockIdx.x * 128;
#pragma unroll
  for (int j = 0; j < 8; ++j) pool_l[j * 256 + t] = 0.f;
#pragma unroll
  for (int i = 0; i < 8; ++i) {
    int id = t + i * 256;
    int row = id >> 4, k8 = id & 15;
    f16x8 v = {0, 0, 0, 0, 0, 0, 0, 0};
    if (r0 + row < n) v = ((const f16x8*)in)[(size_t)(r0 + row) * 16 + k8];
    *(f16x8*)&xs[row * 136 + k8 * 8] = v;
  }
  int lane = t & 63, w = t >> 6;
  int l16 = lane & 15, lk = (lane >> 4) * 8;
  int rw = w * 32;
  int g0 = batch[r0];
  int g4[2][4];
  int rbase = r0 + rw + (lane >> 4) * 4;
#pragma unroll
  for (int fr = 0; fr < 2; ++fr)
#pragma unroll
    for (int j = 0; j < 4; ++j) {
      int row = rbase + fr * 16 + j;
      g4[fr][j] = (row < n) ? batch[row] : -1;
    }
  for (int h = 0; h < 2; ++h) {
    if (h) __syncthreads();             // all waves done reading chunk-0 wt
#pragma unroll
    for (int i = 0; i < 8; ++i) {
      int id = t + i * 256;             // 0..2047 = 128 cols x 16 chunks
      int c = id >> 4, k8 = id & 15;
      *(f16x8*)&wt[c * 136 + k8 * 8] = ((const f16x8*)Wt)[(h * 128 + c) * 16 + k8];
    }
    __syncthreads();
    f32x4 acc[2][8];
#pragma unroll
    for (int fr = 0; fr < 2; ++fr)
#pragma unroll
      for (int fc = 0; fc < 8; ++fc) acc[fr][fc] = (f32x4){0.f, 0.f, 0.f, 0.f};
#pragma unroll
    for (int kk = 0; kk < 4; ++kk) {
      int klo = kk * 32 + lk;
      f16x8 a0 = *(const f16x8*)&xs[(rw + l16) * 136 + klo];
      f16x8 a1 = *(const f16x8*)&xs[(rw + 16 + l16) * 136 + klo];
#pragma unroll
      for (int fc = 0; fc < 8; ++fc) {
        f16x8 b = *(const f16x8*)&wt[(fc * 16 + l16) * 136 + klo];
        acc[0][fc] = __builtin_amdgcn_mfma_f32_16x16x32_f16(a0, b, acc[0][fc], 0, 0, 0);
        acc[1][fc] = __builtin_amdgcn_mfma_f32_16x16x32_f16(a1, b, acc[1][fc], 0, 0, 0);
      }
    }
    // pooled epilogue: run-compress the 4 consecutive rows each lane holds
#pragma unroll
    for (int fc = 0; fc < 8; ++fc) {
      int col = h * 128 + fc * 16 + l16;
      float bv = bias[col];
#pragma unroll
      for (int fr = 0; fr < 2; ++fr) {
        f32x4 a = acc[fr][fc];
        float run = fmaxf(a[0] + bv, 0.f);
#pragma unroll
        for (int j = 1; j < 4; ++j) {
          float v = fmaxf(a[j] + bv, 0.f);
          if (g4[fr][j] == g4[fr][j - 1]) run += v;
          else {
            int g = g4[fr][j - 1];
            if (g >= 0) {
              int d = g - g0;
              if (d >= 0 && d < 8) atomicAdd(&pool_l[d * 256 + col], run);
              else atomicAdd(&pool[g * 256 + col], run);
            }
            run = v;
          }
        }
        int g = g4[fr][3];
        if (g >= 0) {
          int d = g - g0;
          if (d >= 0 && d < 8) atomicAdd(&pool_l[d * 256 + col], run);
          else atomicAdd(&pool[g * 256 + col], run);
        }
      }
    }
  }
  __syncthreads();
#pragma unroll
  for (int j = 0; j < 8; ++j) {
    int g = g0 + j;
    float v = pool_l[j * 256 + t];
    if (g < GRAPHS && v != 0.f) atomicAdd(&pool[g * 256 + t], v);
  }
}

// ---------------- graph boundaries + LayerNorm finalize ----------------
__global__ void k_starts(const int* __restrict__ batch, int* __restrict__ starts, int n) {
  int g = threadIdx.x;
  if (g > GRAPHS) return;
  int lo = 0, hi = n;
  while (lo < hi) { int mid = (lo + hi) >> 1; if (batch[mid] < g) lo = mid + 1; else hi = mid; }
  starts[g] = lo;
}

__global__ void k_final(const float* __restrict__ pool, const int* __restrict__ starts,
                        const float* __restrict__ gamma, const float* __restrict__ beta,
                        float* __restrict__ out) {
  __shared__ float2 red[256];
  int g = blockIdx.x, ch = threadIdx.x;
  int cnt = starts[g + 1] - starts[g];
  float p = pool[g * 256 + ch] / fmaxf((float)cnt, 1.f);
  red[ch] = make_float2(p, p * p);
  __syncthreads();
  for (int off = 128; off > 0; off >>= 1) {
    if (ch < off) { red[ch].x += red[ch + off].x; red[ch].y += red[ch + off].y; }
    __syncthreads();
  }
  float mu = red[0].x * (1.f / 256.f);
  float var = red[0].y * (1.f / 256.f) - mu * mu;
  out[g * 256 + ch] = (p - mu) * rsqrtf(var + 1e-5f) * gamma[ch] + beta[ch];
}

extern "C" void kernel_launch(void* const* d_in, const int* in_sizes, int n_in,
                              void* d_out, int out_size, void* d_ws, size_t ws_size,
                              hipStream_t stream) {
  const float* x     = (const float*)d_in[0];
  const int*   ei    = (const int*)d_in[1];
  const int*   batch = (const int*)d_in[2];
  const float* W11 = (const float*)d_in[3];  const float* b11 = (const float*)d_in[4];
  const float* W12 = (const float*)d_in[5];  const float* b12 = (const float*)d_in[6];
  const float* W21 = (const float*)d_in[7];  const float* b21 = (const float*)d_in[8];
  const float* W22 = (const float*)d_in[9];  const float* b22 = (const float*)d_in[10];
  const float* gamma = (const float*)d_in[11];
  const float* beta  = (const float*)d_in[12];
  float* out = (float*)d_out;

  int n = in_sizes[0] / 128;   // 100000
  int e = in_sizes[1] / 2;     // 1600000
  const int* src = ei;
  const int* dstv = ei + e;

  char* ws = (char*)d_ws;
  auto alloc = [&](size_t bytes) { char* p = ws; ws += (bytes + 15) & ~(size_t)15; return p; };
  _Float16* P0 = (_Float16*)alloc((size_t)n * 128 * 2);
  _Float16* P1 = (_Float16*)alloc((size_t)n * 128 * 2);
  _Float16* P2 = (_Float16*)alloc((size_t)n * 128 * 2);
  float* pool = (float*)alloc((size_t)GRAPHS * 256 * 4);
  int* deg    = (int*)alloc((size_t)n * 4);
  int* ptr    = (int*)alloc((size_t)(n + 1) * 4);
  int* cur    = (int*)alloc((size_t)n * 4);
  int* csr    = (int*)alloc((size_t)e * 4);
  int* bs     = (int*)alloc(256 * 4);
  int* starts = (int*)alloc((GRAPHS + 1) * 4);
  _Float16* w11t = (_Float16*)alloc(128 * 128 * 2);
  _Float16* w12t = (_Float16*)alloc(128 * 128 * 2);
  _Float16* w21t = (_Float16*)alloc(128 * 128 * 2);
  _Float16* w22t = (_Float16*)alloc(256 * 128 * 2);

  hipMemsetAsync(deg, 0, (size_t)n * 4, stream);
  hipMemsetAsync(pool, 0, (size_t)GRAPHS * 256 * 4, stream);

  int nb = (n + 1023) / 1024;
  int eb = (e + 255) / 256;
  k_count<<<eb, 256, 0, stream>>>(dstv, deg, e);
  k_scan1<<<nb, 256, 0, stream>>>(deg, bs, n);
  k_scan2<<<1, 256, 0, stream>>>(bs, nb);
  k_scan3<<<nb, 256, 0, stream>>>(deg, bs, ptr, cur, n, e);
  k_fill<<<eb, 256, 0, stream>>>(src, dstv, cur, csr, e);
  k_starts<<<1, 256, 0, stream>>>(batch, starts, n);
  k_wprep<<<128, 128, 0, stream>>>(W11, w11t, 128);
  k_wprep<<<128, 128, 0, stream>>>(W12, w12t, 128);
  k_wprep<<<128, 128, 0, stream>>>(W21, w21t, 128);
  k_wprep<<<256, 128, 0, stream>>>(W22, w22t, 256);
  k_cvt<<<(n * 32 + 255) / 256, 256, 0, stream>>>(x, P0, n * 32);

  int gb = (n + 127) / 128;
  int ab = (n * 64 + 255) / 256;

  k_agg_h<<<ab, 256, 0, stream>>>(P0, P1, ptr, csr, n);             // P1 = x + agg(x)
  k_gemm128_f16<<<gb, 256, 0, stream>>>(P1, w11t, b11, P2, n);      // P2 = relu(P1@W11+b11)
  k_gemm128_f16<<<gb, 256, 0, stream>>>(P2, w12t, b12, P0, n);      // P0 = h1
  k_agg_h<<<ab, 256, 0, stream>>>(P0, P1, ptr, csr, n);             // P1 = h1 + agg(h1)
  k_gemm128_f16<<<gb, 256, 0, stream>>>(P1, w21t, b21, P2, n);      // P2 = relu(P1@W21+b21)
  k_gemm_pool_f16<<<gb, 256, 0, stream>>>(P2, w22t, b22, batch, pool, n);
  k_final<<<GRAPHS, 256, 0, stream>>>(pool, starts, gamma, beta, out);
}

// Round 6
// 456.905 us; speedup vs baseline: 1.1782x; 1.1782x over previous
//
#include <hip/hip_runtime.h>

#define GRAPHS 128
#define CHUNKC 8000

typedef _Float16 f16x8 __attribute__((ext_vector_type(8)));
typedef _Float16 f16x4 __attribute__((ext_vector_type(4)));
typedef _Float16 f16x2 __attribute__((ext_vector_type(2)));
typedef float f32x4 __attribute__((ext_vector_type(4)));

// ============ CSR build: bucket counting sort, XCD-local writes ============
// bucket = dst >> 9 (512 nodes/bucket). Each (wg, bucket) range of the
// partitioned edge array is written by exactly one workgroup (coalesced), and
// each bucket's csr segment is scattered by exactly one workgroup (one XCD's
// L2 owns the lines) -- kills the 100MB partial-line writeback seen in r4/r5.

__global__ void k_hist(const int* __restrict__ dst, int* __restrict__ histG,
                       int e, int NB, int NW) {
  __shared__ int h[256];
  int t = threadIdx.x, w = blockIdx.x;
  h[t] = 0; __syncthreads();
  int lo = w * CHUNKC, hi = min(lo + CHUNKC, e);
  for (int i = lo + t; i < hi; i += 256) atomicAdd(&h[dst[i] >> 9], 1);
  __syncthreads();
  if (t < NB) histG[t * NW + w] = h[t];
}

__global__ void k_scanh(const int* __restrict__ histG, int* __restrict__ off, int N) {
  __shared__ int s[256];
  int t = threadIdx.x;
  int C = (N + 255) / 256;
  int lo = t * C, hi = min(lo + C, N);
  int sum = 0;
  for (int i = lo; i < hi; ++i) sum += histG[i];
  s[t] = sum; __syncthreads();
  for (int o = 1; o < 256; o <<= 1) {
    int x = (t >= o) ? s[t - o] : 0;
    __syncthreads(); s[t] += x; __syncthreads();
  }
  int run = s[t] - sum;  // exclusive base
  for (int i = lo; i < hi; ++i) { int v = histG[i]; off[i] = run; run += v; }
}

__global__ void k_part(const int* __restrict__ src, const int* __restrict__ dst,
                       const int* __restrict__ histG, const int* __restrict__ off,
                       int* __restrict__ part, int e, int NB, int NW) {
  __shared__ int hist[256], lbA[256], lbB[256], stmp[256];
  __shared__ int els[CHUNKC];
  int t = threadIdx.x, w = blockIdx.x;
  int hv = (t < NB) ? histG[t * NW + w] : 0;
  hist[t] = hv; stmp[t] = hv; __syncthreads();
  for (int o = 1; o < 256; o <<= 1) {
    int x = (t >= o) ? stmp[t - o] : 0;
    __syncthreads(); stmp[t] += x; __syncthreads();
  }
  lbA[t] = stmp[t] - hv; lbB[t] = stmp[t] - hv;
  __syncthreads();
  int lo = w * CHUNKC, hi = min(lo + CHUNKC, e);
  for (int i = lo + t; i < hi; i += 256) {
    int d = dst[i];
    int p = atomicAdd(&lbB[d >> 9], 1);
    els[p] = src[i] | ((d & 511) << 17);   // src < 2^17, dstlow < 2^9
  }
  __syncthreads();
  int ln = t & 63, wv = t >> 6;
  for (int b = wv; b < NB; b += 4) {
    int c = hist[b], lb = lbA[b];
    long g = off[b * NW + w];
    for (int j = ln; j < c; j += 64) part[g + j] = els[lb + j];
  }
}

__global__ void k_csrb(const int* __restrict__ part, const int* __restrict__ off,
                       int* __restrict__ ptr, int* __restrict__ csr,
                       int e, int NB, int NW, int n) {
  __shared__ int nh[512], ncur[512], stmp[256];
  int t = threadIdx.x, b = blockIdx.x;
  int s0 = off[b * NW];
  int e0 = (b + 1 < NB) ? off[(b + 1) * NW] : e;
  nh[t] = 0; nh[t + 256] = 0; __syncthreads();
  for (int i = s0 + t; i < e0; i += 256) atomicAdd(&nh[((unsigned)part[i]) >> 17], 1);
  __syncthreads();
  int v0 = nh[2 * t], v1 = nh[2 * t + 1];
  int ps = v0 + v1;
  stmp[t] = ps; __syncthreads();
  for (int o = 1; o < 256; o <<= 1) {
    int x = (t >= o) ? stmp[t - o] : 0;
    __syncthreads(); stmp[t] += x; __syncthreads();
  }
  int base = stmp[t] - ps;
  __syncthreads();
  nh[2 * t] = base;   nh[2 * t + 1] = base + v0;
  ncur[2 * t] = base; ncur[2 * t + 1] = base + v0;
  __syncthreads();
#pragma unroll
  for (int q = 0; q < 2; ++q) {
    int vv = t + q * 256;
    int node = (b << 9) + vv;
    if (node <= n) ptr[node] = s0 + nh[vv];   // covers sentinel ptr[n]=e
  }
  for (int i = s0 + t; i < e0; i += 256) {
    int u = part[i];
    int p = atomicAdd(&ncur[((unsigned)u) >> 17], 1);
    csr[s0 + p] = u & 0x1FFFF;   // single-wg 32KB region: one XCD owns lines
  }
}

// ---------------- fp32 -> f16 conversion (x only) ----------------
__global__ void k_cvt(const float* __restrict__ in, _Float16* __restrict__ out, int total4) {
  int i = blockIdx.x * 256 + threadIdx.x;
  if (i >= total4) return;
  float4 v = ((const float4*)in)[i];
  f16x4 h = { (_Float16)v.x, (_Float16)v.y, (_Float16)v.z, (_Float16)v.w };
  ((f16x4*)out)[i] = h;
}

// ------------- aggregation (f16 in/out, fp32 accum): out[i] = in[i] + sum_N in[j] -------------
__global__ void k_agg_h(const _Float16* __restrict__ in, _Float16* __restrict__ out,
                        const int* __restrict__ ptr, const int* __restrict__ csr, int n) {
  int gid = blockIdx.x * 256 + threadIdx.x;
  int node = gid >> 6, lane = gid & 63;
  if (node >= n) return;
  const f16x2* inp = (const f16x2*)in;
  f16x2 v = inp[(size_t)node * 64 + lane];
  float ax[8], ay[8];
  ax[0] = (float)v[0]; ay[0] = (float)v[1];
#pragma unroll
  for (int i = 1; i < 8; ++i) { ax[i] = 0.f; ay[i] = 0.f; }
  int s = ptr[node], e2 = ptr[node + 1];
  int idx = s;
  for (; idx + 8 <= e2; idx += 8) {
    f16x2 w[8];
#pragma unroll
    for (int u = 0; u < 8; ++u) w[u] = inp[(size_t)csr[idx + u] * 64 + lane];
#pragma unroll
    for (int u = 0; u < 8; ++u) { ax[u] += (float)w[u][0]; ay[u] += (float)w[u][1]; }
  }
  if (idx + 4 <= e2) {
    f16x2 w[4];
#pragma unroll
    for (int u = 0; u < 4; ++u) w[u] = inp[(size_t)csr[idx + u] * 64 + lane];
#pragma unroll
    for (int u = 0; u < 4; ++u) { ax[u] += (float)w[u][0]; ay[u] += (float)w[u][1]; }
    idx += 4;
  }
  for (; idx < e2; ++idx) {
    f16x2 w0 = inp[(size_t)csr[idx] * 64 + lane];
    ax[0] += (float)w0[0]; ay[0] += (float)w0[1];
  }
  float rx = ((ax[0] + ax[1]) + (ax[2] + ax[3])) + ((ax[4] + ax[5]) + (ax[6] + ax[7]));
  float ry = ((ay[0] + ay[1]) + (ay[2] + ay[3])) + ((ay[4] + ay[5]) + (ay[6] + ay[7]));
  f16x2 r = { (_Float16)rx, (_Float16)ry };
  ((f16x2*)out)[(size_t)node * 64 + lane] = r;
}

// -------- weight prep: W[k][c] fp32 -> Wt[c][k] f16 (grid = C, 128 threads) --------
__global__ void k_wprep(const float* __restrict__ W, _Float16* __restrict__ Wt, int C) {
  int c = blockIdx.x, k = threadIdx.x;
  Wt[c * 128 + k] = (_Float16)W[k * C + c];
}

// ------------- MFMA f16 GEMM: out = relu(in @ W + b), 128 -> 128, f16 in/out -------------
__launch_bounds__(256)
__global__ void k_gemm128_f16(const _Float16* __restrict__ in, const _Float16* __restrict__ Wt,
                              const float* __restrict__ bias, _Float16* __restrict__ out, int n) {
  __shared__ _Float16 xs[128 * 136];
  __shared__ _Float16 wt[128 * 136];
  int t = threadIdx.x;
  int r0 = blockIdx.x * 128;
#pragma unroll
  for (int i = 0; i < 8; ++i) {
    int id = t + i * 256;           // 0..2047 = 128 rows x 16 chunks
    int row = id >> 4, k8 = id & 15;
    f16x8 v = {0, 0, 0, 0, 0, 0, 0, 0};
    if (r0 + row < n) v = ((const f16x8*)in)[(size_t)(r0 + row) * 16 + k8];
    *(f16x8*)&xs[row * 136 + k8 * 8] = v;
  }
#pragma unroll
  for (int i = 0; i < 8; ++i) {
    int id = t + i * 256;           // 0..2047 = 128 cols x 16 chunks
    int c = id >> 4, k8 = id & 15;
    *(f16x8*)&wt[c * 136 + k8 * 8] = ((const f16x8*)Wt)[c * 16 + k8];
  }
  __syncthreads();
  int lane = t & 63, w = t >> 6;
  int l16 = lane & 15, lk = (lane >> 4) * 8;
  int rw = w * 32;
  f32x4 acc[2][8];
#pragma unroll
  for (int fr = 0; fr < 2; ++fr)
#pragma unroll
    for (int fc = 0; fc < 8; ++fc) acc[fr][fc] = (f32x4){0.f, 0.f, 0.f, 0.f};
#pragma unroll
  for (int kk = 0; kk < 4; ++kk) {
    int klo = kk * 32 + lk;
    f16x8 a0 = *(const f16x8*)&xs[(rw + l16) * 136 + klo];
    f16x8 a1 = *(const f16x8*)&xs[(rw + 16 + l16) * 136 + klo];
#pragma unroll
    for (int fc = 0; fc < 8; ++fc) {
      f16x8 b = *(const f16x8*)&wt[(fc * 16 + l16) * 136 + klo];
      acc[0][fc] = __builtin_amdgcn_mfma_f32_16x16x32_f16(a0, b, acc[0][fc], 0, 0, 0);
      acc[1][fc] = __builtin_amdgcn_mfma_f32_16x16x32_f16(a1, b, acc[1][fc], 0, 0, 0);
    }
  }
  int rbase = r0 + rw + (lane >> 4) * 4;
#pragma unroll
  for (int fr = 0; fr < 2; ++fr)
#pragma unroll
    for (int fc = 0; fc < 8; ++fc) {
      int col = fc * 16 + l16;
      float bv = bias[col];
#pragma unroll
      for (int j = 0; j < 4; ++j) {
        int row = rbase + fr * 16 + j;
        if (row < n) out[(size_t)row * 128 + col] = (_Float16)fmaxf(acc[fr][fc][j] + bv, 0.f);
      }
    }
}

// ------- final GEMM 128 -> 256 (two 128-col chunks) fused with mean-pool sums -------
__launch_bounds__(256)
__global__ void k_gemm_pool_f16(const _Float16* __restrict__ in, const _Float16* __restrict__ Wt,
                                const float* __restrict__ bias, const int* __restrict__ batch,
                                float* __restrict__ pool, int n) {
  __shared__ _Float16 xs[128 * 136];
  __shared__ _Float16 wt[128 * 136];
  __shared__ float pool_l[8 * 256];
  int t = threadIdx.x;
  int r0 = blockIdx.x * 128;
#pragma unroll
  for (int j = 0; j < 8; ++j) pool_l[j * 256 + t] = 0.f;
#pragma unroll
  for (int i = 0; i < 8; ++i) {
    int id = t + i * 256;
    int row = id >> 4, k8 = id & 15;
    f16x8 v = {0, 0, 0, 0, 0, 0, 0, 0};
    if (r0 + row < n) v = ((const f16x8*)in)[(size_t)(r0 + row) * 16 + k8];
    *(f16x8*)&xs[row * 136 + k8 * 8] = v;
  }
  int lane = t & 63, w = t >> 6;
  int l16 = lane & 15, lk = (lane >> 4) * 8;
  int rw = w * 32;
  int g0 = batch[r0];
  int g4[2][4];
  int rbase = r0 + rw + (lane >> 4) * 4;
#pragma unroll
  for (int fr = 0; fr < 2; ++fr)
#pragma unroll
    for (int j = 0; j < 4; ++j) {
      int row = rbase + fr * 16 + j;
      g4[fr][j] = (row < n) ? batch[row] : -1;
    }
  for (int h = 0; h < 2; ++h) {
    if (h) __syncthreads();
#pragma unroll
    for (int i = 0; i < 8; ++i) {
      int id = t + i * 256;
      int c = id >> 4, k8 = id & 15;
      *(f16x8*)&wt[c * 136 + k8 * 8] = ((const f16x8*)Wt)[(h * 128 + c) * 16 + k8];
    }
    __syncthreads();
    f32x4 acc[2][8];
#pragma unroll
    for (int fr = 0; fr < 2; ++fr)
#pragma unroll
      for (int fc = 0; fc < 8; ++fc) acc[fr][fc] = (f32x4){0.f, 0.f, 0.f, 0.f};
#pragma unroll
    for (int kk = 0; kk < 4; ++kk) {
      int klo = kk * 32 + lk;
      f16x8 a0 = *(const f16x8*)&xs[(rw + l16) * 136 + klo];
      f16x8 a1 = *(const f16x8*)&xs[(rw + 16 + l16) * 136 + klo];
#pragma unroll
      for (int fc = 0; fc < 8; ++fc) {
        f16x8 b = *(const f16x8*)&wt[(fc * 16 + l16) * 136 + klo];
        acc[0][fc] = __builtin_amdgcn_mfma_f32_16x16x32_f16(a0, b, acc[0][fc], 0, 0, 0);
        acc[1][fc] = __builtin_amdgcn_mfma_f32_16x16x32_f16(a1, b, acc[1][fc], 0, 0, 0);
      }
    }
#pragma unroll
    for (int fc = 0; fc < 8; ++fc) {
      int col = h * 128 + fc * 16 + l16;
      float bv = bias[col];
#pragma unroll
      for (int fr = 0; fr < 2; ++fr) {
        f32x4 a = acc[fr][fc];
        float run = fmaxf(a[0] + bv, 0.f);
#pragma unroll
        for (int j = 1; j < 4; ++j) {
          float v = fmaxf(a[j] + bv, 0.f);
          if (g4[fr][j] == g4[fr][j - 1]) run += v;
          else {
            int g = g4[fr][j - 1];
            if (g >= 0) {
              int d = g - g0;
              if (d >= 0 && d < 8) atomicAdd(&pool_l[d * 256 + col], run);
              else atomicAdd(&pool[g * 256 + col], run);
            }
            run = v;
          }
        }
        int g = g4[fr][3];
        if (g >= 0) {
          int d = g - g0;
          if (d >= 0 && d < 8) atomicAdd(&pool_l[d * 256 + col], run);
          else atomicAdd(&pool[g * 256 + col], run);
        }
      }
    }
  }
  __syncthreads();
#pragma unroll
  for (int j = 0; j < 8; ++j) {
    int g = g0 + j;
    float v = pool_l[j * 256 + t];
    if (g < GRAPHS && v != 0.f) atomicAdd(&pool[g * 256 + t], v);
  }
}

// ---------------- graph boundaries + LayerNorm finalize ----------------
__global__ void k_starts(const int* __restrict__ batch, int* __restrict__ starts, int n) {
  int g = threadIdx.x;
  if (g > GRAPHS) return;
  int lo = 0, hi = n;
  while (lo < hi) { int mid = (lo + hi) >> 1; if (batch[mid] < g) lo = mid + 1; else hi = mid; }
  starts[g] = lo;
}

__global__ void k_final(const float* __restrict__ pool, const int* __restrict__ starts,
                        const float* __restrict__ gamma, const float* __restrict__ beta,
                        float* __restrict__ out) {
  __shared__ float2 red[256];
  int g = blockIdx.x, ch = threadIdx.x;
  int cnt = starts[g + 1] - starts[g];
  float p = pool[g * 256 + ch] / fmaxf((float)cnt, 1.f);
  red[ch] = make_float2(p, p * p);
  __syncthreads();
  for (int off = 128; off > 0; off >>= 1) {
    if (ch < off) { red[ch].x += red[ch + off].x; red[ch].y += red[ch + off].y; }
    __syncthreads();
  }
  float mu = red[0].x * (1.f / 256.f);
  float var = red[0].y * (1.f / 256.f) - mu * mu;
  out[g * 256 + ch] = (p - mu) * rsqrtf(var + 1e-5f) * gamma[ch] + beta[ch];
}

extern "C" void kernel_launch(void* const* d_in, const int* in_sizes, int n_in,
                              void* d_out, int out_size, void* d_ws, size_t ws_size,
                              hipStream_t stream) {
  const float* x     = (const float*)d_in[0];
  const int*   ei    = (const int*)d_in[1];
  const int*   batch = (const int*)d_in[2];
  const float* W11 = (const float*)d_in[3];  const float* b11 = (const float*)d_in[4];
  const float* W12 = (const float*)d_in[5];  const float* b12 = (const float*)d_in[6];
  const float* W21 = (const float*)d_in[7];  const float* b21 = (const float*)d_in[8];
  const float* W22 = (const float*)d_in[9];  const float* b22 = (const float*)d_in[10];
  const float* gamma = (const float*)d_in[11];
  const float* beta  = (const float*)d_in[12];
  float* out = (float*)d_out;

  int n = in_sizes[0] / 128;   // 100000
  int e = in_sizes[1] / 2;     // 1600000
  const int* src = ei;
  const int* dstv = ei + e;

  int NB = (n + 511) >> 9;                 // 196 buckets
  int NW = (e + CHUNKC - 1) / CHUNKC;      // 200 workgroups

  char* ws = (char*)d_ws;
  auto alloc = [&](size_t bytes) { char* p = ws; ws += (bytes + 15) & ~(size_t)15; return p; };
  _Float16* P0 = (_Float16*)alloc((size_t)n * 128 * 2);
  _Float16* P1 = (_Float16*)alloc((size_t)n * 128 * 2);
  _Float16* P2 = (_Float16*)alloc((size_t)n * 128 * 2);
  float* pool  = (float*)alloc((size_t)GRAPHS * 256 * 4);
  int* ptr     = (int*)alloc((size_t)(n + 1) * 4);
  int* csr     = (int*)alloc((size_t)e * 4);
  int* part    = (int*)alloc((size_t)e * 4);
  int* histG   = (int*)alloc((size_t)NB * NW * 4);
  int* off     = (int*)alloc((size_t)NB * NW * 4);
  int* starts  = (int*)alloc((GRAPHS + 1) * 4);
  _Float16* w11t = (_Float16*)alloc(128 * 128 * 2);
  _Float16* w12t = (_Float16*)alloc(128 * 128 * 2);
  _Float16* w21t = (_Float16*)alloc(128 * 128 * 2);
  _Float16* w22t = (_Float16*)alloc(256 * 128 * 2);

  hipMemsetAsync(pool, 0, (size_t)GRAPHS * 256 * 4, stream);

  k_hist <<<NW, 256, 0, stream>>>(dstv, histG, e, NB, NW);
  k_scanh<<<1, 256, 0, stream>>>(histG, off, NB * NW);
  k_part <<<NW, 256, 0, stream>>>(src, dstv, histG, off, part, e, NB, NW);
  k_csrb <<<NB, 256, 0, stream>>>(part, off, ptr, csr, e, NB, NW, n);
  k_starts<<<1, 256, 0, stream>>>(batch, starts, n);
  k_wprep<<<128, 128, 0, stream>>>(W11, w11t, 128);
  k_wprep<<<128, 128, 0, stream>>>(W12, w12t, 128);
  k_wprep<<<128, 128, 0, stream>>>(W21, w21t, 128);
  k_wprep<<<256, 128, 0, stream>>>(W22, w22t, 256);
  k_cvt<<<(n * 32 + 255) / 256, 256, 0, stream>>>(x, P0, n * 32);

  int gb = (n + 127) / 128;
  int ab = (n * 64 + 255) / 256;

  k_agg_h<<<ab, 256, 0, stream>>>(P0, P1, ptr, csr, n);             // P1 = x + agg(x)
  k_gemm128_f16<<<gb, 256, 0, stream>>>(P1, w11t, b11, P2, n);      // P2 = relu(P1@W11+b11)
  k_gemm128_f16<<<gb, 256, 0, stream>>>(P2, w12t, b12, P0, n);      // P0 = h1
  k_agg_h<<<ab, 256, 0, stream>>>(P0, P1, ptr, csr, n);             // P1 = h1 + agg(h1)
  k_gemm128_f16<<<gb, 256, 0, stream>>>(P1, w21t, b21, P2, n);      // P2 = relu(P1@W21+b21)
  k_gemm_pool_f16<<<gb, 256, 0, stream>>>(P2, w22t, b22, batch, pool, n);
  k_final<<<GRAPHS, 256, 0, stream>>>(pool, starts, gamma, beta, out);
}

// Round 7
// 370.144 us; speedup vs baseline: 1.4543x; 1.2344x over previous
//
#include <hip/hip_runtime.h>

#define GRAPHS 128
#define CHUNKC 8000

typedef _Float16 f16x8 __attribute__((ext_vector_type(8)));
typedef _Float16 f16x4 __attribute__((ext_vector_type(4)));
typedef _Float16 f16x2 __attribute__((ext_vector_type(2)));
typedef float f32x4 __attribute__((ext_vector_type(4)));

// ============ CSR build: bucket counting sort, XCD-local writes ============
__global__ void k_hist(const int* __restrict__ dst, int* __restrict__ histG,
                       int e, int NB, int NW) {
  __shared__ int h[256];
  int t = threadIdx.x, w = blockIdx.x;
  h[t] = 0; __syncthreads();
  int lo = w * CHUNKC, hi = min(lo + CHUNKC, e);
  for (int i = lo + t; i < hi; i += 256) atomicAdd(&h[dst[i] >> 9], 1);
  __syncthreads();
  if (t < NB) histG[t * NW + w] = h[t];
}

__global__ void k_scanh(const int* __restrict__ histG, int* __restrict__ off, int N) {
  __shared__ int s[256];
  int t = threadIdx.x;
  int C = (N + 255) / 256;
  int lo = t * C, hi = min(lo + C, N);
  int sum = 0;
  for (int i = lo; i < hi; ++i) sum += histG[i];
  s[t] = sum; __syncthreads();
  for (int o = 1; o < 256; o <<= 1) {
    int x = (t >= o) ? s[t - o] : 0;
    __syncthreads(); s[t] += x; __syncthreads();
  }
  int run = s[t] - sum;  // exclusive base
  for (int i = lo; i < hi; ++i) { int v = histG[i]; off[i] = run; run += v; }
}

__global__ void k_part(const int* __restrict__ src, const int* __restrict__ dst,
                       const int* __restrict__ histG, const int* __restrict__ off,
                       int* __restrict__ part, int e, int NB, int NW) {
  __shared__ int hist[256], lbA[256], lbB[256], stmp[256];
  __shared__ int els[CHUNKC];
  int t = threadIdx.x, w = blockIdx.x;
  int hv = (t < NB) ? histG[t * NW + w] : 0;
  hist[t] = hv; stmp[t] = hv; __syncthreads();
  for (int o = 1; o < 256; o <<= 1) {
    int x = (t >= o) ? stmp[t - o] : 0;
    __syncthreads(); stmp[t] += x; __syncthreads();
  }
  lbA[t] = stmp[t] - hv; lbB[t] = stmp[t] - hv;
  __syncthreads();
  int lo = w * CHUNKC, hi = min(lo + CHUNKC, e);
  for (int i = lo + t; i < hi; i += 256) {
    int d = dst[i];
    int p = atomicAdd(&lbB[d >> 9], 1);
    els[p] = src[i] | ((d & 511) << 17);   // src < 2^17, dstlow < 2^9
  }
  __syncthreads();
  int ln = t & 63, wv = t >> 6;
  for (int b = wv; b < NB; b += 4) {
    int c = hist[b], lb = lbA[b];
    long g = off[b * NW + w];
    for (int j = ln; j < c; j += 64) part[g + j] = els[lb + j];
  }
}

__global__ void k_csrb(const int* __restrict__ part, const int* __restrict__ off,
                       int* __restrict__ ptr, int* __restrict__ csr,
                       int e, int NB, int NW, int n) {
  __shared__ int nh[512], ncur[512], stmp[256];
  int t = threadIdx.x, b = blockIdx.x;
  int s0 = off[b * NW];
  int e0 = (b + 1 < NB) ? off[(b + 1) * NW] : e;
  nh[t] = 0; nh[t + 256] = 0; __syncthreads();
  for (int i = s0 + t; i < e0; i += 256) atomicAdd(&nh[((unsigned)part[i]) >> 17], 1);
  __syncthreads();
  int v0 = nh[2 * t], v1 = nh[2 * t + 1];
  int ps = v0 + v1;
  stmp[t] = ps; __syncthreads();
  for (int o = 1; o < 256; o <<= 1) {
    int x = (t >= o) ? stmp[t - o] : 0;
    __syncthreads(); stmp[t] += x; __syncthreads();
  }
  int base = stmp[t] - ps;
  __syncthreads();
  nh[2 * t] = base;   nh[2 * t + 1] = base + v0;
  ncur[2 * t] = base; ncur[2 * t + 1] = base + v0;
  __syncthreads();
#pragma unroll
  for (int q = 0; q < 2; ++q) {
    int vv = t + q * 256;
    int node = (b << 9) + vv;
    if (node <= n) ptr[node] = s0 + nh[vv];   // covers sentinel ptr[n]=e
  }
  for (int i = s0 + t; i < e0; i += 256) {
    int u = part[i];
    int p = atomicAdd(&ncur[((unsigned)u) >> 17], 1);
    csr[s0 + p] = u & 0x1FFFF;
  }
}

// ---------------- fp32 -> f16 conversion (x only) ----------------
__global__ void k_cvt(const float* __restrict__ in, _Float16* __restrict__ out, int total4) {
  int i = blockIdx.x * 256 + threadIdx.x;
  if (i >= total4) return;
  float4 v = ((const float4*)in)[i];
  f16x4 h = { (_Float16)v.x, (_Float16)v.y, (_Float16)v.z, (_Float16)v.w };
  ((f16x4*)out)[i] = h;
}

// ------------- aggregation: out[i] = in[i] + sum_N in[j], f16 in/out, f32 accum -------
// one wave per node. Index block preloaded (csr[s+lane]) + __shfl broadcast;
// 16-deep gather batches; invalid slots -> zero row at index n (L1-hot).
__global__ void k_agg_h(const _Float16* __restrict__ in, _Float16* __restrict__ out,
                        const int* __restrict__ ptr, const int* __restrict__ csr, int n) {
  int gid = blockIdx.x * 256 + threadIdx.x;
  int node = gid >> 6, lane = gid & 63;
  if (node >= n) return;
  const f16x2* inp = (const f16x2*)in;
  f16x2 v = inp[node * 64 + lane];
  float ax[8], ay[8];
  ax[0] = (float)v[0]; ay[0] = (float)v[1];
#pragma unroll
  for (int i = 1; i < 8; ++i) { ax[i] = 0.f; ay[i] = 0.f; }
  int s = ptr[node], deg = ptr[node + 1] - s;
  for (int seg = 0; seg < deg; seg += 64) {
    int segn = min(deg - seg, 64);
    int my = (seg + lane < deg) ? csr[s + seg + lane] : n;
    for (int b2 = 0; b2 < segn; b2 += 16) {
      int jj[16];
#pragma unroll
      for (int u = 0; u < 16; ++u) jj[u] = __shfl(my, b2 + u);
      f16x2 w[16];
#pragma unroll
      for (int u = 0; u < 16; ++u) w[u] = inp[jj[u] * 64 + lane];
#pragma unroll
      for (int u = 0; u < 16; ++u) {
        int a = u & 7;
        ax[a] += (float)w[u][0]; ay[a] += (float)w[u][1];
      }
    }
  }
  float rx = ((ax[0] + ax[1]) + (ax[2] + ax[3])) + ((ax[4] + ax[5]) + (ax[6] + ax[7]));
  float ry = ((ay[0] + ay[1]) + (ay[2] + ay[3])) + ((ay[4] + ay[5]) + (ay[6] + ay[7]));
  f16x2 r = { (_Float16)rx, (_Float16)ry };
  ((f16x2*)out)[node * 64 + lane] = r;
}

// -------- weight prep (all 4 mats): W[k][c] fp32 -> Wt[c][k] f16 --------
__global__ void k_wprep_all(const float* __restrict__ W11, const float* __restrict__ W12,
                            const float* __restrict__ W21, const float* __restrict__ W22,
                            _Float16* __restrict__ w11t, _Float16* __restrict__ w12t,
                            _Float16* __restrict__ w21t, _Float16* __restrict__ w22t) {
  int b = blockIdx.x, k = threadIdx.x;
  const float* W; _Float16* Wt; int c, C;
  if (b < 128)      { W = W11; Wt = w11t; c = b;       C = 128; }
  else if (b < 256) { W = W12; Wt = w12t; c = b - 128; C = 128; }
  else if (b < 384) { W = W21; Wt = w21t; c = b - 256; C = 128; }
  else              { W = W22; Wt = w22t; c = b - 384; C = 256; }
  Wt[c * 128 + k] = (_Float16)W[k * C + c];
}

// ------- fused MLP: out = relu(relu(in@WA+bA)@WB+bB), 128->128->128 -------
// 256-row tile, 512 threads (8 waves x 32 rows). h written back into each
// wave's OWN xs rows (no cross-wave dependency -> no extra barrier).
__launch_bounds__(512)
__global__ void k_mlp128(const _Float16* __restrict__ in, const _Float16* __restrict__ WtA,
                         const float* __restrict__ bA, const _Float16* __restrict__ WtB,
                         const float* __restrict__ bB, _Float16* __restrict__ out, int n) {
  __shared__ _Float16 xs[256 * 136];
  __shared__ _Float16 wa[128 * 136];
  __shared__ _Float16 wb[128 * 136];
  int t = threadIdx.x;
  int r0 = blockIdx.x * 256;
#pragma unroll
  for (int i = 0; i < 8; ++i) {          // 4096 = 256 rows x 16 chunks
    int id = t + i * 512;
    int row = id >> 4, k8 = id & 15;
    f16x8 v = {0, 0, 0, 0, 0, 0, 0, 0};
    if (r0 + row < n) v = ((const f16x8*)in)[(size_t)(r0 + row) * 16 + k8];
    *(f16x8*)&xs[row * 136 + k8 * 8] = v;
  }
#pragma unroll
  for (int i = 0; i < 4; ++i) {          // 2048 = 128 cols x 16 chunks
    int id = t + i * 512;
    int c = id >> 4, k8 = id & 15;
    *(f16x8*)&wa[c * 136 + k8 * 8] = ((const f16x8*)WtA)[c * 16 + k8];
    *(f16x8*)&wb[c * 136 + k8 * 8] = ((const f16x8*)WtB)[c * 16 + k8];
  }
  __syncthreads();
  int lane = t & 63, w = t >> 6;
  int l16 = lane & 15, lk = (lane >> 4) * 8;
  int rw = w * 32;
  int rloc = rw + (lane >> 4) * 4;
  f32x4 acc[2][8];
  // ---- layer A
#pragma unroll
  for (int fr = 0; fr < 2; ++fr)
#pragma unroll
    for (int fc = 0; fc < 8; ++fc) acc[fr][fc] = (f32x4){0.f, 0.f, 0.f, 0.f};
#pragma unroll
  for (int kk = 0; kk < 4; ++kk) {
    int klo = kk * 32 + lk;
    f16x8 a0 = *(const f16x8*)&xs[(rw + l16) * 136 + klo];
    f16x8 a1 = *(const f16x8*)&xs[(rw + 16 + l16) * 136 + klo];
#pragma unroll
    for (int fc = 0; fc < 8; ++fc) {
      f16x8 b = *(const f16x8*)&wa[(fc * 16 + l16) * 136 + klo];
      acc[0][fc] = __builtin_amdgcn_mfma_f32_16x16x32_f16(a0, b, acc[0][fc], 0, 0, 0);
      acc[1][fc] = __builtin_amdgcn_mfma_f32_16x16x32_f16(a1, b, acc[1][fc], 0, 0, 0);
    }
  }
#pragma unroll
  for (int fr = 0; fr < 2; ++fr)
#pragma unroll
    for (int fc = 0; fc < 8; ++fc) {
      int col = fc * 16 + l16;
      float bv = bA[col];
#pragma unroll
      for (int j = 0; j < 4; ++j)
        xs[(rloc + fr * 16 + j) * 136 + col] = (_Float16)fmaxf(acc[fr][fc][j] + bv, 0.f);
    }
  // ---- layer B (reads only this wave's rows; compiler orders via lgkmcnt)
#pragma unroll
  for (int fr = 0; fr < 2; ++fr)
#pragma unroll
    for (int fc = 0; fc < 8; ++fc) acc[fr][fc] = (f32x4){0.f, 0.f, 0.f, 0.f};
#pragma unroll
  for (int kk = 0; kk < 4; ++kk) {
    int klo = kk * 32 + lk;
    f16x8 a0 = *(const f16x8*)&xs[(rw + l16) * 136 + klo];
    f16x8 a1 = *(const f16x8*)&xs[(rw + 16 + l16) * 136 + klo];
#pragma unroll
    for (int fc = 0; fc < 8; ++fc) {
      f16x8 b = *(const f16x8*)&wb[(fc * 16 + l16) * 136 + klo];
      acc[0][fc] = __builtin_amdgcn_mfma_f32_16x16x32_f16(a0, b, acc[0][fc], 0, 0, 0);
      acc[1][fc] = __builtin_amdgcn_mfma_f32_16x16x32_f16(a1, b, acc[1][fc], 0, 0, 0);
    }
  }
#pragma unroll
  for (int fr = 0; fr < 2; ++fr)
#pragma unroll
    for (int fc = 0; fc < 8; ++fc) {
      int col = fc * 16 + l16;
      float bv = bB[col];
#pragma unroll
      for (int j = 0; j < 4; ++j) {
        int row = r0 + rloc + fr * 16 + j;
        if (row < n) out[(size_t)row * 128 + col] = (_Float16)fmaxf(acc[fr][fc][j] + bv, 0.f);
      }
    }
}

// ------- fused MLP + pool: relu(relu(in@W21+b21)@W22+b22) summed per graph -------
__launch_bounds__(512)
__global__ void k_mlp_pool(const _Float16* __restrict__ in, const _Float16* __restrict__ WtA,
                           const float* __restrict__ bA, const _Float16* __restrict__ WtB,
                           const float* __restrict__ bB, const int* __restrict__ batch,
                           float* __restrict__ pool, int n) {
  __shared__ _Float16 xs[256 * 136];
  __shared__ _Float16 wa[128 * 136];
  __shared__ _Float16 wb[128 * 136];
  __shared__ float pool_l[8 * 256];
  int t = threadIdx.x;
  int r0 = blockIdx.x * 256;
#pragma unroll
  for (int j = 0; j < 4; ++j) pool_l[j * 512 + t] = 0.f;
#pragma unroll
  for (int i = 0; i < 8; ++i) {
    int id = t + i * 512;
    int row = id >> 4, k8 = id & 15;
    f16x8 v = {0, 0, 0, 0, 0, 0, 0, 0};
    if (r0 + row < n) v = ((const f16x8*)in)[(size_t)(r0 + row) * 16 + k8];
    *(f16x8*)&xs[row * 136 + k8 * 8] = v;
  }
#pragma unroll
  for (int i = 0; i < 4; ++i) {
    int id = t + i * 512;
    int c = id >> 4, k8 = id & 15;
    *(f16x8*)&wa[c * 136 + k8 * 8] = ((const f16x8*)WtA)[c * 16 + k8];
    *(f16x8*)&wb[c * 136 + k8 * 8] = ((const f16x8*)WtB)[c * 16 + k8];  // W22 cols 0..127
  }
  __syncthreads();
  int lane = t & 63, w = t >> 6;
  int l16 = lane & 15, lk = (lane >> 4) * 8;
  int rw = w * 32;
  int rloc = rw + (lane >> 4) * 4;
  int g0 = batch[r0];
  int g4[2][4];
#pragma unroll
  for (int fr = 0; fr < 2; ++fr)
#pragma unroll
    for (int j = 0; j < 4; ++j) {
      int row = r0 + rloc + fr * 16 + j;
      g4[fr][j] = (row < n) ? batch[row] : -1;
    }
  f32x4 acc[2][8];
  // ---- layer A (W21)
#pragma unroll
  for (int fr = 0; fr < 2; ++fr)
#pragma unroll
    for (int fc = 0; fc < 8; ++fc) acc[fr][fc] = (f32x4){0.f, 0.f, 0.f, 0.f};
#pragma unroll
  for (int kk = 0; kk < 4; ++kk) {
    int klo = kk * 32 + lk;
    f16x8 a0 = *(const f16x8*)&xs[(rw + l16) * 136 + klo];
    f16x8 a1 = *(const f16x8*)&xs[(rw + 16 + l16) * 136 + klo];
#pragma unroll
    for (int fc = 0; fc < 8; ++fc) {
      f16x8 b = *(const f16x8*)&wa[(fc * 16 + l16) * 136 + klo];
      acc[0][fc] = __builtin_amdgcn_mfma_f32_16x16x32_f16(a0, b, acc[0][fc], 0, 0, 0);
      acc[1][fc] = __builtin_amdgcn_mfma_f32_16x16x32_f16(a1, b, acc[1][fc], 0, 0, 0);
    }
  }
#pragma unroll
  for (int fr = 0; fr < 2; ++fr)
#pragma unroll
    for (int fc = 0; fc < 8; ++fc) {
      int col = fc * 16 + l16;
      float bv = bA[col];
#pragma unroll
      for (int j = 0; j < 4; ++j)
        xs[(rloc + fr * 16 + j) * 136 + col] = (_Float16)fmaxf(acc[fr][fc][j] + bv, 0.f);
    }
  // ---- layer B (W22), two 128-col halves
  for (int h = 0; h < 2; ++h) {
    if (h) {
      __syncthreads();                 // all waves done with wb half-0
#pragma unroll
      for (int i = 0; i < 4; ++i) {
        int id = t + i * 512;
        int c = id >> 4, k8 = id & 15;
        *(f16x8*)&wb[c * 136 + k8 * 8] = ((const f16x8*)WtB)[(128 + c) * 16 + k8];
      }
      __syncthreads();
    }
#pragma unroll
    for (int fr = 0; fr < 2; ++fr)
#pragma unroll
      for (int fc = 0; fc < 8; ++fc) acc[fr][fc] = (f32x4){0.f, 0.f, 0.f, 0.f};
#pragma unroll
    for (int kk = 0; kk < 4; ++kk) {
      int klo = kk * 32 + lk;
      f16x8 a0 = *(const f16x8*)&xs[(rw + l16) * 136 + klo];
      f16x8 a1 = *(const f16x8*)&xs[(rw + 16 + l16) * 136 + klo];
#pragma unroll
      for (int fc = 0; fc < 8; ++fc) {
        f16x8 b = *(const f16x8*)&wb[(fc * 16 + l16) * 136 + klo];
        acc[0][fc] = __builtin_amdgcn_mfma_f32_16x16x32_f16(a0, b, acc[0][fc], 0, 0, 0);
        acc[1][fc] = __builtin_amdgcn_mfma_f32_16x16x32_f16(a1, b, acc[1][fc], 0, 0, 0);
      }
    }
#pragma unroll
    for (int fc = 0; fc < 8; ++fc) {
      int col = h * 128 + fc * 16 + l16;
      float bv = bB[col];
#pragma unroll
      for (int fr = 0; fr < 2; ++fr) {
        f32x4 a = acc[fr][fc];
        float run = fmaxf(a[0] + bv, 0.f);
#pragma unroll
        for (int j = 1; j < 4; ++j) {
          float v = fmaxf(a[j] + bv, 0.f);
          if (g4[fr][j] == g4[fr][j - 1]) run += v;
          else {
            int g = g4[fr][j - 1];
            if (g >= 0) {
              int d = g - g0;
              if (d >= 0 && d < 8) atomicAdd(&pool_l[d * 256 + col], run);
              else atomicAdd(&pool[g * 256 + col], run);
            }
            run = v;
          }
        }
        int g = g4[fr][3];
        if (g >= 0) {
          int d = g - g0;
          if (d >= 0 && d < 8) atomicAdd(&pool_l[d * 256 + col], run);
          else atomicAdd(&pool[g * 256 + col], run);
        }
      }
    }
  }
  __syncthreads();
#pragma unroll
  for (int j = 0; j < 4; ++j) {
    int idx = j * 512 + t;
    int g = g0 + (idx >> 8), col = idx & 255;
    float v = pool_l[idx];
    if (g < GRAPHS && v != 0.f) atomicAdd(&pool[g * 256 + col], v);
  }
}

// ---------------- graph boundaries + LayerNorm finalize ----------------
__global__ void k_starts(const int* __restrict__ batch, int* __restrict__ starts, int n) {
  int g = threadIdx.x;
  if (g > GRAPHS) return;
  int lo = 0, hi = n;
  while (lo < hi) { int mid = (lo + hi) >> 1; if (batch[mid] < g) lo = mid + 1; else hi = mid; }
  starts[g] = lo;
}

__global__ void k_final(const float* __restrict__ pool, const int* __restrict__ starts,
                        const float* __restrict__ gamma, const float* __restrict__ beta,
                        float* __restrict__ out) {
  __shared__ float2 red[256];
  int g = blockIdx.x, ch = threadIdx.x;
  int cnt = starts[g + 1] - starts[g];
  float p = pool[g * 256 + ch] / fmaxf((float)cnt, 1.f);
  red[ch] = make_float2(p, p * p);
  __syncthreads();
  for (int off = 128; off > 0; off >>= 1) {
    if (ch < off) { red[ch].x += red[ch + off].x; red[ch].y += red[ch + off].y; }
    __syncthreads();
  }
  float mu = red[0].x * (1.f / 256.f);
  float var = red[0].y * (1.f / 256.f) - mu * mu;
  out[g * 256 + ch] = (p - mu) * rsqrtf(var + 1e-5f) * gamma[ch] + beta[ch];
}

extern "C" void kernel_launch(void* const* d_in, const int* in_sizes, int n_in,
                              void* d_out, int out_size, void* d_ws, size_t ws_size,
                              hipStream_t stream) {
  const float* x     = (const float*)d_in[0];
  const int*   ei    = (const int*)d_in[1];
  const int*   batch = (const int*)d_in[2];
  const float* W11 = (const float*)d_in[3];  const float* b11 = (const float*)d_in[4];
  const float* W12 = (const float*)d_in[5];  const float* b12 = (const float*)d_in[6];
  const float* W21 = (const float*)d_in[7];  const float* b21 = (const float*)d_in[8];
  const float* W22 = (const float*)d_in[9];  const float* b22 = (const float*)d_in[10];
  const float* gamma = (const float*)d_in[11];
  const float* beta  = (const float*)d_in[12];
  float* out = (float*)d_out;

  int n = in_sizes[0] / 128;   // 100000
  int e = in_sizes[1] / 2;     // 1600000
  const int* src = ei;
  const int* dstv = ei + e;

  int NB = (n + 511) >> 9;                 // 196 buckets
  int NW = (e + CHUNKC - 1) / CHUNKC;      // 200 workgroups

  char* ws = (char*)d_ws;
  auto alloc = [&](size_t bytes) { char* p = ws; ws += (bytes + 15) & ~(size_t)15; return p; };
  _Float16* P0 = (_Float16*)alloc((size_t)(n + 1) * 128 * 2);  // +1: zero row for agg padding
  _Float16* P1 = (_Float16*)alloc((size_t)(n + 1) * 128 * 2);
  float* pool  = (float*)alloc((size_t)GRAPHS * 256 * 4);
  int* ptr     = (int*)alloc((size_t)(n + 1) * 4);
  int* csr     = (int*)alloc((size_t)e * 4);
  int* part    = (int*)alloc((size_t)e * 4);
  int* histG   = (int*)alloc((size_t)NB * NW * 4);
  int* off     = (int*)alloc((size_t)NB * NW * 4);
  int* starts  = (int*)alloc((GRAPHS + 1) * 4);
  _Float16* w11t = (_Float16*)alloc(128 * 128 * 2);
  _Float16* w12t = (_Float16*)alloc(128 * 128 * 2);
  _Float16* w21t = (_Float16*)alloc(128 * 128 * 2);
  _Float16* w22t = (_Float16*)alloc(256 * 128 * 2);

  hipMemsetAsync(pool, 0, (size_t)GRAPHS * 256 * 4, stream);
  hipMemsetAsync(P0 + (size_t)n * 128, 0, 256, stream);   // zero gather-pad row

  k_hist <<<NW, 256, 0, stream>>>(dstv, histG, e, NB, NW);
  k_scanh<<<1, 256, 0, stream>>>(histG, off, NB * NW);
  k_part <<<NW, 256, 0, stream>>>(src, dstv, histG, off, part, e, NB, NW);
  k_csrb <<<NB, 256, 0, stream>>>(part, off, ptr, csr, e, NB, NW, n);
  k_starts<<<1, 256, 0, stream>>>(batch, starts, n);
  k_wprep_all<<<640, 128, 0, stream>>>(W11, W12, W21, W22, w11t, w12t, w21t, w22t);
  k_cvt<<<(n * 32 + 255) / 256, 256, 0, stream>>>(x, P0, n * 32);

  int mb = (n + 255) / 256;
  int ab = (n * 64 + 255) / 256;

  k_agg_h<<<ab, 256, 0, stream>>>(P0, P1, ptr, csr, n);                    // P1 = x + agg(x)
  k_mlp128<<<mb, 512, 0, stream>>>(P1, w11t, b11, w12t, b12, P0, n);       // P0 = h1
  k_agg_h<<<ab, 256, 0, stream>>>(P0, P1, ptr, csr, n);                    // P1 = h1 + agg(h1)
  k_mlp_pool<<<mb, 512, 0, stream>>>(P1, w21t, b21, w22t, b22, batch, pool, n);
  k_final<<<GRAPHS, 256, 0, stream>>>(pool, starts, gamma, beta, out);
}

// Round 8
// 317.725 us; speedup vs baseline: 1.6942x; 1.1650x over previous
//
#include <hip/hip_runtime.h>

#define GRAPHS 128
#define CHUNKC 8000

typedef _Float16 f16x8 __attribute__((ext_vector_type(8)));
typedef _Float16 f16x4 __attribute__((ext_vector_type(4)));
typedef _Float16 f16x2 __attribute__((ext_vector_type(2)));
typedef float f32x4 __attribute__((ext_vector_type(4)));

// ============ CSR build: bucket counting sort, XCD-local writes ============
__global__ void k_hist(const int* __restrict__ dst, int* __restrict__ histG,
                       int e, int NB, int NW) {
  __shared__ int h[256];
  int t = threadIdx.x, w = blockIdx.x;
  h[t] = 0; __syncthreads();
  int lo = w * CHUNKC, hi = min(lo + CHUNKC, e);
  for (int i = lo + t; i < hi; i += 256) atomicAdd(&h[dst[i] >> 9], 1);
  __syncthreads();
  if (t < NB) histG[t * NW + w] = h[t];
}

// ---- 3-phase parallel exclusive scan of N ints (replaces 1-block k_scanh) ----
__global__ void k_scanA(const int* __restrict__ in, int* __restrict__ out,
                        int* __restrict__ bsum, int N) {
  __shared__ int s[256];
  int t = threadIdx.x, b = blockIdx.x;
  int base = b * 1024 + t * 4;
  int v[4]; int tot = 0;
#pragma unroll
  for (int j = 0; j < 4; ++j) { int i = base + j; v[j] = (i < N) ? in[i] : 0; tot += v[j]; }
  s[t] = tot; __syncthreads();
  for (int o = 1; o < 256; o <<= 1) {
    int x = (t >= o) ? s[t - o] : 0;
    __syncthreads(); s[t] += x; __syncthreads();
  }
  int run = s[t] - tot;
#pragma unroll
  for (int j = 0; j < 4; ++j) { int i = base + j; if (i < N) out[i] = run; run += v[j]; }
  if (t == 255) bsum[b] = s[255];
}

__global__ void k_scanB(int* bsum, int nb) {  // 1 block, nb <= 256
  __shared__ int s[256];
  int t = threadIdx.x;
  int v = (t < nb) ? bsum[t] : 0;
  s[t] = v; __syncthreads();
  for (int o = 1; o < 256; o <<= 1) {
    int x = (t >= o) ? s[t - o] : 0;
    __syncthreads(); s[t] += x; __syncthreads();
  }
  if (t < nb) bsum[t] = s[t] - v;
}

__global__ void k_scanC(int* __restrict__ out, const int* __restrict__ bsum, int N) {
  int i = blockIdx.x * 256 + threadIdx.x;
  if (i < N) out[i] += bsum[i >> 10];
}

__global__ void k_part(const int* __restrict__ src, const int* __restrict__ dst,
                       const int* __restrict__ histG, const int* __restrict__ off,
                       int* __restrict__ part, int e, int NB, int NW) {
  __shared__ int hist[256], lbA[256], lbB[256], stmp[256];
  __shared__ int els[CHUNKC];
  int t = threadIdx.x, w = blockIdx.x;
  int hv = (t < NB) ? histG[t * NW + w] : 0;
  hist[t] = hv; stmp[t] = hv; __syncthreads();
  for (int o = 1; o < 256; o <<= 1) {
    int x = (t >= o) ? stmp[t - o] : 0;
    __syncthreads(); stmp[t] += x; __syncthreads();
  }
  lbA[t] = stmp[t] - hv; lbB[t] = stmp[t] - hv;
  __syncthreads();
  int lo = w * CHUNKC, hi = min(lo + CHUNKC, e);
  for (int i = lo + t; i < hi; i += 256) {
    int d = dst[i];
    int p = atomicAdd(&lbB[d >> 9], 1);
    els[p] = src[i] | ((d & 511) << 17);   // src < 2^17, dstlow < 2^9
  }
  __syncthreads();
  int ln = t & 63, wv = t >> 6;
  for (int b = wv; b < NB; b += 4) {
    int c = hist[b], lb = lbA[b];
    long g = off[b * NW + w];
    for (int j = ln; j < c; j += 64) part[g + j] = els[lb + j];
  }
}

__global__ void k_csrb(const int* __restrict__ part, const int* __restrict__ off,
                       int* __restrict__ ptr, int* __restrict__ csr,
                       int e, int NB, int NW, int n) {
  __shared__ int nh[512], ncur[512], stmp[256];
  int t = threadIdx.x, b = blockIdx.x;
  int s0 = off[b * NW];
  int e0 = (b + 1 < NB) ? off[(b + 1) * NW] : e;
  nh[t] = 0; nh[t + 256] = 0; __syncthreads();
  for (int i = s0 + t; i < e0; i += 256) atomicAdd(&nh[((unsigned)part[i]) >> 17], 1);
  __syncthreads();
  int v0 = nh[2 * t], v1 = nh[2 * t + 1];
  int ps = v0 + v1;
  stmp[t] = ps; __syncthreads();
  for (int o = 1; o < 256; o <<= 1) {
    int x = (t >= o) ? stmp[t - o] : 0;
    __syncthreads(); stmp[t] += x; __syncthreads();
  }
  int base = stmp[t] - ps;
  __syncthreads();
  nh[2 * t] = base;   nh[2 * t + 1] = base + v0;
  ncur[2 * t] = base; ncur[2 * t + 1] = base + v0;
  __syncthreads();
#pragma unroll
  for (int q = 0; q < 2; ++q) {
    int vv = t + q * 256;
    int node = (b << 9) + vv;
    if (node <= n) ptr[node] = s0 + nh[vv];   // covers sentinel ptr[n]=e
  }
  for (int i = s0 + t; i < e0; i += 256) {
    int u = part[i];
    int p = atomicAdd(&ncur[((unsigned)u) >> 17], 1);
    csr[s0 + p] = u & 0x1FFFF;
  }
}

// ---------------- fp32 -> f16 conversion (x only) ----------------
__global__ void k_cvt(const float* __restrict__ in, _Float16* __restrict__ out, int total4) {
  int i = blockIdx.x * 256 + threadIdx.x;
  if (i >= total4) return;
  float4 v = ((const float4*)in)[i];
  f16x4 h = { (_Float16)v.x, (_Float16)v.y, (_Float16)v.z, (_Float16)v.w };
  ((f16x4*)out)[i] = h;
}

// ------------- aggregation: out[i] = in[i] + sum_N in[j], f16, f32 accum -------------
// one wave per node, WIDE gather: lane loads f16x8 (16B); 16 lanes cover a row;
// a wave gathers 4 rows/instr, 8 loads (32 rows) in flight. Partials live in
// row-groups rg=lane>>4; combined by shfl_xor(16|32). Overrun -> zero row (idx n).
__global__ void k_agg_h(const _Float16* __restrict__ in, _Float16* __restrict__ out,
                        const int* __restrict__ ptr, const int* __restrict__ csr, int n) {
  int gid = blockIdx.x * 256 + threadIdx.x;
  int node = gid >> 6, lane = gid & 63;
  if (node >= n) return;
  const f16x8* inp = (const f16x8*)in;
  int cb = lane & 15, rg = lane >> 4;
  f16x8 self = inp[(size_t)node * 16 + cb];
  float acc[8];
#pragma unroll
  for (int c = 0; c < 8; ++c) acc[c] = (rg == 0) ? (float)self[c] : 0.f;
  int s = ptr[node], deg = ptr[node + 1] - s;
  for (int seg = 0; seg < deg; seg += 64) {
    int my = (seg + lane < deg) ? csr[s + seg + lane] : n;
    int segn = min(deg - seg, 64);
    for (int b2 = 0; b2 < segn; b2 += 32) {
      int jj[8]; f16x8 w[8];
#pragma unroll
      for (int u = 0; u < 8; ++u) jj[u] = __shfl(my, b2 + u * 4 + rg);
#pragma unroll
      for (int u = 0; u < 8; ++u) w[u] = inp[(size_t)jj[u] * 16 + cb];
#pragma unroll
      for (int u = 0; u < 8; ++u)
#pragma unroll
        for (int c = 0; c < 8; ++c) acc[c] += (float)w[u][c];
    }
  }
#pragma unroll
  for (int c = 0; c < 8; ++c) {
    acc[c] += __shfl_xor(acc[c], 16);
    acc[c] += __shfl_xor(acc[c], 32);
  }
  if (rg == 0) {
    f16x8 r;
#pragma unroll
    for (int c = 0; c < 8; ++c) r[c] = (_Float16)acc[c];
    ((f16x8*)out)[(size_t)node * 16 + cb] = r;
  }
}

// -------- weight prep (all 4 mats): W[k][c] fp32 -> Wt[c][k] f16 --------
__global__ void k_wprep_all(const float* __restrict__ W11, const float* __restrict__ W12,
                            const float* __restrict__ W21, const float* __restrict__ W22,
                            _Float16* __restrict__ w11t, _Float16* __restrict__ w12t,
                            _Float16* __restrict__ w21t, _Float16* __restrict__ w22t) {
  int b = blockIdx.x, k = threadIdx.x;
  const float* W; _Float16* Wt; int c, C;
  if (b < 128)      { W = W11; Wt = w11t; c = b;       C = 128; }
  else if (b < 256) { W = W12; Wt = w12t; c = b - 128; C = 128; }
  else if (b < 384) { W = W21; Wt = w21t; c = b - 256; C = 128; }
  else              { W = W22; Wt = w22t; c = b - 384; C = 256; }
  Wt[c * 128 + k] = (_Float16)W[k * C + c];
}

// ------- fused MLP: out = relu(relu(in@WA+bA)@WB+bB), 128->128->128 -------
__launch_bounds__(512)
__global__ void k_mlp128(const _Float16* __restrict__ in, const _Float16* __restrict__ WtA,
                         const float* __restrict__ bA, const _Float16* __restrict__ WtB,
                         const float* __restrict__ bB, _Float16* __restrict__ out, int n) {
  __shared__ _Float16 xs[256 * 136];
  __shared__ _Float16 wa[128 * 136];
  __shared__ _Float16 wb[128 * 136];
  int t = threadIdx.x;
  int r0 = blockIdx.x * 256;
#pragma unroll
  for (int i = 0; i < 8; ++i) {          // 4096 = 256 rows x 16 chunks
    int id = t + i * 512;
    int row = id >> 4, k8 = id & 15;
    f16x8 v = {0, 0, 0, 0, 0, 0, 0, 0};
    if (r0 + row < n) v = ((const f16x8*)in)[(size_t)(r0 + row) * 16 + k8];
    *(f16x8*)&xs[row * 136 + k8 * 8] = v;
  }
#pragma unroll
  for (int i = 0; i < 4; ++i) {          // 2048 = 128 cols x 16 chunks
    int id = t + i * 512;
    int c = id >> 4, k8 = id & 15;
    *(f16x8*)&wa[c * 136 + k8 * 8] = ((const f16x8*)WtA)[c * 16 + k8];
    *(f16x8*)&wb[c * 136 + k8 * 8] = ((const f16x8*)WtB)[c * 16 + k8];
  }
  __syncthreads();
  int lane = t & 63, w = t >> 6;
  int l16 = lane & 15, lk = (lane >> 4) * 8;
  int rw = w * 32;
  int rloc = rw + (lane >> 4) * 4;
  f32x4 acc[2][8];
  // ---- layer A
#pragma unroll
  for (int fr = 0; fr < 2; ++fr)
#pragma unroll
    for (int fc = 0; fc < 8; ++fc) acc[fr][fc] = (f32x4){0.f, 0.f, 0.f, 0.f};
#pragma unroll
  for (int kk = 0; kk < 4; ++kk) {
    int klo = kk * 32 + lk;
    f16x8 a0 = *(const f16x8*)&xs[(rw + l16) * 136 + klo];
    f16x8 a1 = *(const f16x8*)&xs[(rw + 16 + l16) * 136 + klo];
#pragma unroll
    for (int fc = 0; fc < 8; ++fc) {
      f16x8 b = *(const f16x8*)&wa[(fc * 16 + l16) * 136 + klo];
      acc[0][fc] = __builtin_amdgcn_mfma_f32_16x16x32_f16(a0, b, acc[0][fc], 0, 0, 0);
      acc[1][fc] = __builtin_amdgcn_mfma_f32_16x16x32_f16(a1, b, acc[1][fc], 0, 0, 0);
    }
  }
#pragma unroll
  for (int fr = 0; fr < 2; ++fr)
#pragma unroll
    for (int fc = 0; fc < 8; ++fc) {
      int col = fc * 16 + l16;
      float bv = bA[col];
#pragma unroll
      for (int j = 0; j < 4; ++j)
        xs[(rloc + fr * 16 + j) * 136 + col] = (_Float16)fmaxf(acc[fr][fc][j] + bv, 0.f);
    }
  // ---- layer B (reads only this wave's rows; compiler orders via lgkmcnt)
#pragma unroll
  for (int fr = 0; fr < 2; ++fr)
#pragma unroll
    for (int fc = 0; fc < 8; ++fc) acc[fr][fc] = (f32x4){0.f, 0.f, 0.f, 0.f};
#pragma unroll
  for (int kk = 0; kk < 4; ++kk) {
    int klo = kk * 32 + lk;
    f16x8 a0 = *(const f16x8*)&xs[(rw + l16) * 136 + klo];
    f16x8 a1 = *(const f16x8*)&xs[(rw + 16 + l16) * 136 + klo];
#pragma unroll
    for (int fc = 0; fc < 8; ++fc) {
      f16x8 b = *(const f16x8*)&wb[(fc * 16 + l16) * 136 + klo];
      acc[0][fc] = __builtin_amdgcn_mfma_f32_16x16x32_f16(a0, b, acc[0][fc], 0, 0, 0);
      acc[1][fc] = __builtin_amdgcn_mfma_f32_16x16x32_f16(a1, b, acc[1][fc], 0, 0, 0);
    }
  }
#pragma unroll
  for (int fr = 0; fr < 2; ++fr)
#pragma unroll
    for (int fc = 0; fc < 8; ++fc) {
      int col = fc * 16 + l16;
      float bv = bB[col];
#pragma unroll
      for (int j = 0; j < 4; ++j) {
        int row = r0 + rloc + fr * 16 + j;
        if (row < n) out[(size_t)row * 128 + col] = (_Float16)fmaxf(acc[fr][fc][j] + bv, 0.f);
      }
    }
}

// ------- fused MLP + pool: relu(relu(in@W21+b21)@W22+b22) summed per graph -------
__launch_bounds__(512)
__global__ void k_mlp_pool(const _Float16* __restrict__ in, const _Float16* __restrict__ WtA,
                           const float* __restrict__ bA, const _Float16* __restrict__ WtB,
                           const float* __restrict__ bB, const int* __restrict__ batch,
                           float* __restrict__ pool, int n) {
  __shared__ _Float16 xs[256 * 136];
  __shared__ _Float16 wa[128 * 136];
  __shared__ _Float16 wb[128 * 136];
  __shared__ float pool_l[8 * 256];
  int t = threadIdx.x;
  int r0 = blockIdx.x * 256;
#pragma unroll
  for (int j = 0; j < 4; ++j) pool_l[j * 512 + t] = 0.f;
#pragma unroll
  for (int i = 0; i < 8; ++i) {
    int id = t + i * 512;
    int row = id >> 4, k8 = id & 15;
    f16x8 v = {0, 0, 0, 0, 0, 0, 0, 0};
    if (r0 + row < n) v = ((const f16x8*)in)[(size_t)(r0 + row) * 16 + k8];
    *(f16x8*)&xs[row * 136 + k8 * 8] = v;
  }
#pragma unroll
  for (int i = 0; i < 4; ++i) {
    int id = t + i * 512;
    int c = id >> 4, k8 = id & 15;
    *(f16x8*)&wa[c * 136 + k8 * 8] = ((const f16x8*)WtA)[c * 16 + k8];
    *(f16x8*)&wb[c * 136 + k8 * 8] = ((const f16x8*)WtB)[c * 16 + k8];  // W22 cols 0..127
  }
  __syncthreads();
  int lane = t & 63, w = t >> 6;
  int l16 = lane & 15, lk = (lane >> 4) * 8;
  int rw = w * 32;
  int rloc = rw + (lane >> 4) * 4;
  int g0 = batch[r0];
  int g4[2][4];
#pragma unroll
  for (int fr = 0; fr < 2; ++fr)
#pragma unroll
    for (int j = 0; j < 4; ++j) {
      int row = r0 + rloc + fr * 16 + j;
      g4[fr][j] = (row < n) ? batch[row] : -1;
    }
  f32x4 acc[2][8];
  // ---- layer A (W21)
#pragma unroll
  for (int fr = 0; fr < 2; ++fr)
#pragma unroll
    for (int fc = 0; fc < 8; ++fc) acc[fr][fc] = (f32x4){0.f, 0.f, 0.f, 0.f};
#pragma unroll
  for (int kk = 0; kk < 4; ++kk) {
    int klo = kk * 32 + lk;
    f16x8 a0 = *(const f16x8*)&xs[(rw + l16) * 136 + klo];
    f16x8 a1 = *(const f16x8*)&xs[(rw + 16 + l16) * 136 + klo];
#pragma unroll
    for (int fc = 0; fc < 8; ++fc) {
      f16x8 b = *(const f16x8*)&wa[(fc * 16 + l16) * 136 + klo];
      acc[0][fc] = __builtin_amdgcn_mfma_f32_16x16x32_f16(a0, b, acc[0][fc], 0, 0, 0);
      acc[1][fc] = __builtin_amdgcn_mfma_f32_16x16x32_f16(a1, b, acc[1][fc], 0, 0, 0);
    }
  }
#pragma unroll
  for (int fr = 0; fr < 2; ++fr)
#pragma unroll
    for (int fc = 0; fc < 8; ++fc) {
      int col = fc * 16 + l16;
      float bv = bA[col];
#pragma unroll
      for (int j = 0; j < 4; ++j)
        xs[(rloc + fr * 16 + j) * 136 + col] = (_Float16)fmaxf(acc[fr][fc][j] + bv, 0.f);
    }
  // ---- layer B (W22), two 128-col halves
  for (int h = 0; h < 2; ++h) {
    if (h) {
      __syncthreads();                 // all waves done with wb half-0
#pragma unroll
      for (int i = 0; i < 4; ++i) {
        int id = t + i * 512;
        int c = id >> 4, k8 = id & 15;
        *(f16x8*)&wb[c * 136 + k8 * 8] = ((const f16x8*)WtB)[(128 + c) * 16 + k8];
      }
      __syncthreads();
    }
#pragma unroll
    for (int fr = 0; fr < 2; ++fr)
#pragma unroll
      for (int fc = 0; fc < 8; ++fc) acc[fr][fc] = (f32x4){0.f, 0.f, 0.f, 0.f};
#pragma unroll
    for (int kk = 0; kk < 4; ++kk) {
      int klo = kk * 32 + lk;
      f16x8 a0 = *(const f16x8*)&xs[(rw + l16) * 136 + klo];
      f16x8 a1 = *(const f16x8*)&xs[(rw + 16 + l16) * 136 + klo];
#pragma unroll
      for (int fc = 0; fc < 8; ++fc) {
        f16x8 b = *(const f16x8*)&wb[(fc * 16 + l16) * 136 + klo];
        acc[0][fc] = __builtin_amdgcn_mfma_f32_16x16x32_f16(a0, b, acc[0][fc], 0, 0, 0);
        acc[1][fc] = __builtin_amdgcn_mfma_f32_16x16x32_f16(a1, b, acc[1][fc], 0, 0, 0);
      }
    }
#pragma unroll
    for (int fc = 0; fc < 8; ++fc) {
      int col = h * 128 + fc * 16 + l16;
      float bv = bB[col];
#pragma unroll
      for (int fr = 0; fr < 2; ++fr) {
        f32x4 a = acc[fr][fc];
        float run = fmaxf(a[0] + bv, 0.f);
#pragma unroll
        for (int j = 1; j < 4; ++j) {
          float v = fmaxf(a[j] + bv, 0.f);
          if (g4[fr][j] == g4[fr][j - 1]) run += v;
          else {
            int g = g4[fr][j - 1];
            if (g >= 0) {
              int d = g - g0;
              if (d >= 0 && d < 8) atomicAdd(&pool_l[d * 256 + col], run);
              else atomicAdd(&pool[g * 256 + col], run);
            }
            run = v;
          }
        }
        int g = g4[fr][3];
        if (g >= 0) {
          int d = g - g0;
          if (d >= 0 && d < 8) atomicAdd(&pool_l[d * 256 + col], run);
          else atomicAdd(&pool[g * 256 + col], run);
        }
      }
    }
  }
  __syncthreads();
#pragma unroll
  for (int j = 0; j < 4; ++j) {
    int idx = j * 512 + t;
    int g = g0 + (idx >> 8), col = idx & 255;
    float v = pool_l[idx];
    if (g < GRAPHS && v != 0.f) atomicAdd(&pool[g * 256 + col], v);
  }
}

// ---------------- graph boundaries + LayerNorm finalize ----------------
__global__ void k_starts(const int* __restrict__ batch, int* __restrict__ starts, int n) {
  int g = threadIdx.x;
  if (g > GRAPHS) return;
  int lo = 0, hi = n;
  while (lo < hi) { int mid = (lo + hi) >> 1; if (batch[mid] < g) lo = mid + 1; else hi = mid; }
  starts[g] = lo;
}

__global__ void k_final(const float* __restrict__ pool, const int* __restrict__ starts,
                        const float* __restrict__ gamma, const float* __restrict__ beta,
                        float* __restrict__ out) {
  __shared__ float2 red[256];
  int g = blockIdx.x, ch = threadIdx.x;
  int cnt = starts[g + 1] - starts[g];
  float p = pool[g * 256 + ch] / fmaxf((float)cnt, 1.f);
  red[ch] = make_float2(p, p * p);
  __syncthreads();
  for (int off = 128; off > 0; off >>= 1) {
    if (ch < off) { red[ch].x += red[ch + off].x; red[ch].y += red[ch + off].y; }
    __syncthreads();
  }
  float mu = red[0].x * (1.f / 256.f);
  float var = red[0].y * (1.f / 256.f) - mu * mu;
  out[g * 256 + ch] = (p - mu) * rsqrtf(var + 1e-5f) * gamma[ch] + beta[ch];
}

extern "C" void kernel_launch(void* const* d_in, const int* in_sizes, int n_in,
                              void* d_out, int out_size, void* d_ws, size_t ws_size,
                              hipStream_t stream) {
  const float* x     = (const float*)d_in[0];
  const int*   ei    = (const int*)d_in[1];
  const int*   batch = (const int*)d_in[2];
  const float* W11 = (const float*)d_in[3];  const float* b11 = (const float*)d_in[4];
  const float* W12 = (const float*)d_in[5];  const float* b12 = (const float*)d_in[6];
  const float* W21 = (const float*)d_in[7];  const float* b21 = (const float*)d_in[8];
  const float* W22 = (const float*)d_in[9];  const float* b22 = (const float*)d_in[10];
  const float* gamma = (const float*)d_in[11];
  const float* beta  = (const float*)d_in[12];
  float* out = (float*)d_out;

  int n = in_sizes[0] / 128;   // 100000
  int e = in_sizes[1] / 2;     // 1600000
  const int* src = ei;
  const int* dstv = ei + e;

  int NB = (n + 511) >> 9;                 // 196 buckets
  int NW = (e + CHUNKC - 1) / CHUNKC;      // 200 workgroups
  int NS = NB * NW;                        // 39200 scan entries

  char* ws = (char*)d_ws;
  auto alloc = [&](size_t bytes) { char* p = ws; ws += (bytes + 15) & ~(size_t)15; return p; };
  _Float16* P0 = (_Float16*)alloc((size_t)(n + 1) * 128 * 2);  // +1: zero row for agg padding
  _Float16* P1 = (_Float16*)alloc((size_t)(n + 1) * 128 * 2);
  float* pool  = (float*)alloc((size_t)GRAPHS * 256 * 4);
  int* ptr     = (int*)alloc((size_t)(n + 1) * 4);
  int* csr     = (int*)alloc((size_t)e * 4);
  int* part    = (int*)alloc((size_t)e * 4);
  int* histG   = (int*)alloc((size_t)NS * 4);
  int* off     = (int*)alloc((size_t)NS * 4);
  int* bsum    = (int*)alloc(256 * 4);
  int* starts  = (int*)alloc((GRAPHS + 1) * 4);
  _Float16* w11t = (_Float16*)alloc(128 * 128 * 2);
  _Float16* w12t = (_Float16*)alloc(128 * 128 * 2);
  _Float16* w21t = (_Float16*)alloc(128 * 128 * 2);
  _Float16* w22t = (_Float16*)alloc(256 * 128 * 2);

  hipMemsetAsync(pool, 0, (size_t)GRAPHS * 256 * 4, stream);
  hipMemsetAsync(P0 + (size_t)n * 128, 0, 256, stream);   // zero gather-pad row

  int nbk = (NS + 1023) / 1024;            // 39 scan blocks
  k_hist <<<NW, 256, 0, stream>>>(dstv, histG, e, NB, NW);
  k_scanA<<<nbk, 256, 0, stream>>>(histG, off, bsum, NS);
  k_scanB<<<1, 256, 0, stream>>>(bsum, nbk);
  k_scanC<<<(NS + 255) / 256, 256, 0, stream>>>(off, bsum, NS);
  k_part <<<NW, 256, 0, stream>>>(src, dstv, histG, off, part, e, NB, NW);
  k_csrb <<<NB, 256, 0, stream>>>(part, off, ptr, csr, e, NB, NW, n);
  k_starts<<<1, 256, 0, stream>>>(batch, starts, n);
  k_wprep_all<<<640, 128, 0, stream>>>(W11, W12, W21, W22, w11t, w12t, w21t, w22t);
  k_cvt<<<(n * 32 + 255) / 256, 256, 0, stream>>>(x, P0, n * 32);

  int mb = (n + 255) / 256;
  int ab = (n * 64 + 255) / 256;

  k_agg_h<<<ab, 256, 0, stream>>>(P0, P1, ptr, csr, n);                    // P1 = x + agg(x)
  k_mlp128<<<mb, 512, 0, stream>>>(P1, w11t, b11, w12t, b12, P0, n);       // P0 = h1
  k_agg_h<<<ab, 256, 0, stream>>>(P0, P1, ptr, csr, n);                    // P1 = h1 + agg(h1)
  k_mlp_pool<<<mb, 512, 0, stream>>>(P1, w21t, b21, w22t, b22, batch, pool, n);
  k_final<<<GRAPHS, 256, 0, stream>>>(pool, starts, gamma, beta, out);
}